// Round 1
// baseline (82.858 us; speedup 1.0000x reference)
//
#include <hip/hip_runtime.h>

#define NPTS 4096
#define NBATCH 16
#define THREADS 256
#define QPB 256          // queries per block (4 waves x 2 A-frags = 64 q/wave)
#define TPB 2048         // targets per block (blockIdx.z splits the 4096 in 2)
#define TCH 1024         // targets per LDS chunk
#define NCH (TPB / TCH)  // 2 chunks

typedef __attribute__((ext_vector_type(8))) short short8;
typedef __attribute__((ext_vector_type(16))) float float16v;

static __device__ __forceinline__ unsigned short f2bf(float f) {
  unsigned int u = __builtin_bit_cast(unsigned int, f);
  u = (u + 0x7FFFu + ((u >> 16) & 1u)) >> 16;  // RNE
  return (unsigned short)u;
}
static __device__ __forceinline__ float bf2f(unsigned short h) {
  unsigned int u = ((unsigned int)h) << 16;
  return __builtin_bit_cast(float, u);
}
// Swizzled ushort offset of half-record h of target j (32B flat records,
// 16B-block XOR keyed by j's 128B group) -- staging writes & B-frag reads
// land on distinct banks (R8: verified correct, absmax 0.0).
static __device__ __forceinline__ int toff(int j, int h) {
  return (j * 16 + h * 8) ^ (((j >> 2) & 7) << 3);
}

// R11: 2 A-frags/wave (64 queries) halves LDS B-frag reads per MFMA -- the
// kernel was LDS-read-pipe bound (~24.6k cyc/CU of ds_read_b128; all waves
// re-read identical B-frags; reads scale as 1/A-frags). To keep 1024 blocks
// -> 4 blocks/CU -> 4 waves/SIMD (R8 showed 2 waves/SIMD latency-exposed),
// blockIdx.z now encodes dir AND target-half: each block scans 2048 targets.
// Row-mins are partial across the 2 halves -> each block stores 256 per-query
// partial d2 mins to ws (plain coalesced stores, 1MB), and chamfer_finish
// does min(half0,half1) -> sqrt -> sum. LDS = 32KB tgt + 8KB qry = 40KB
// (qry reused as qmin buffer) = exactly 4 blocks/CU. Register budget:
// acc 32 + d-temps 32 (pairwise fold) + af 8 + b 8 + addr ~15 ~= 110 < 128.
__global__ __launch_bounds__(THREADS)
__attribute__((amdgpu_waves_per_eu(4, 4)))
void chamfer_mfma(const float* __restrict__ shape,
                  const float* __restrict__ tmpl,
                  float* __restrict__ ws) {
  __shared__ unsigned short tgt[TCH * 16];  // 32 KB swizzled records
  __shared__ unsigned short qry[QPB * 16];  // 8 KB flat records; reused as qmin

  const int qc = blockIdx.x;       // 0..15 query chunk
  const int b = blockIdx.y;        // batch
  const int dir = blockIdx.z & 1;  // direction
  const int tc = blockIdx.z >> 1;  // target half
  const float* Pb = (dir == 0 ? shape : tmpl) + (size_t)b * NPTS * 3;
  const float* Tb = (dir == 0 ? tmpl : shape) + (size_t)b * NPTS * 3;

  const int tid = threadIdx.x;
  const int lane = tid & 63;
  const int wave = tid >> 6;
  const int n = lane & 31;   // MFMA row/col
  const int kg = lane >> 5;  // K-group: k = kg*8 + j

  // ---- Stage 256 queries: u=-2p split + p2 split record (1 per thread) ----
  {
    const int qg = qc * QPB + tid;
    const float px = Pb[3 * qg + 0], py = Pb[3 * qg + 1], pz = Pb[3 * qg + 2];
    const float ux = -2.0f * px, uy = -2.0f * py, uz = -2.0f * pz;
    const float p2 = fmaf(px, px, fmaf(py, py, pz * pz));
    const unsigned short hx = f2bf(ux), hy = f2bf(uy), hz = f2bf(uz);
    const unsigned short lx = f2bf(ux - bf2f(hx)), ly = f2bf(uy - bf2f(hy)),
                         lz = f2bf(uz - bf2f(hz));
    const unsigned short h2 = f2bf(p2), l2 = f2bf(p2 - bf2f(h2));
    const unsigned short ONE = 0x3F80;
    short8 v0, v1;
    v0[0] = hx; v0[1] = hx; v0[2] = lx; v0[3] = hy;
    v0[4] = hy; v0[5] = ly; v0[6] = hz; v0[7] = hz;
    v1[0] = lz; v1[1] = ONE; v1[2] = ONE; v1[3] = h2;
    v1[4] = l2; v1[5] = 0;  v1[6] = 0;  v1[7] = 0;
    *(short8*)&qry[tid * 16] = v0;
    *(short8*)&qry[tid * 16 + 8] = v1;
  }
  __syncthreads();

  // ---- Two A-frags: wave w owns queries w*64 .. w*64+63 ----
  const short8 af0 = *(const short8*)&qry[(wave * 64 + n) * 16 + kg * 8];
  const short8 af1 = *(const short8*)&qry[(wave * 64 + 32 + n) * 16 + kg * 8];

  const float INF = 3.402823466e38f;
  float acc0[16], acc1[16];
  #pragma unroll
  for (int r = 0; r < 16; ++r) { acc0[r] = INF; acc1[r] = INF; }
  const float16v z = {};

  const float4* T4 = (const float4*)Tb;
  for (int ch = 0; ch < NCH; ++ch) {
    __syncthreads();
    // ---- Stage 1024 targets (4/thread: 3 float4 loads -> swizzled recs) ----
    {
      const int g = tc * (TPB / 4) + ch * (TCH / 4) + tid;
      const float4 a = T4[g * 3 + 0];
      const float4 c = T4[g * 3 + 1];
      const float4 d = T4[g * 3 + 2];
      const float X[4] = {a.x, a.w, c.z, d.y};
      const float Y[4] = {a.y, c.x, c.w, d.z};
      const float Z[4] = {a.z, c.y, d.x, d.w};
      #pragma unroll
      for (int p = 0; p < 4; ++p) {
        const float x = X[p], y = Y[p], zc = Z[p];
        const float t2 = fmaf(x, x, fmaf(y, y, zc * zc));
        const unsigned short hx = f2bf(x), hy = f2bf(y), hz = f2bf(zc);
        const unsigned short lx = f2bf(x - bf2f(hx)), ly = f2bf(y - bf2f(hy)),
                             lz = f2bf(zc - bf2f(hz));
        const unsigned short h2 = f2bf(t2), l2 = f2bf(t2 - bf2f(h2));
        const unsigned short ONE = 0x3F80;
        short8 v0, v1;
        v0[0] = hx; v0[1] = lx; v0[2] = hx; v0[3] = hy;
        v0[4] = ly; v0[5] = hy; v0[6] = hz; v0[7] = lz;
        v1[0] = hz; v1[1] = h2; v1[2] = l2; v1[3] = ONE;
        v1[4] = ONE; v1[5] = 0; v1[6] = 0; v1[7] = 0;
        const int j = tid * 4 + p;
        *(short8*)&tgt[toff(j, 0)] = v0;
        *(short8*)&tgt[toff(j, 1)] = v1;
      }
    }
    __syncthreads();

    // ---- 16 tile-pairs: 2 reads -> 4 MFMA (2 per A-frag) -> 32 min3 ----
    // Pairwise fold (d0,d1 -> acc0 before issuing d2,d3) caps live temps.
    for (int tp = 0; tp < TCH / 64; ++tp) {
      const short8 b0 = *(const short8*)&tgt[toff(tp * 64 + n, kg)];
      const short8 b1 = *(const short8*)&tgt[toff(tp * 64 + 32 + n, kg)];
      float16v d0 = __builtin_amdgcn_mfma_f32_32x32x16_bf16(af0, b0, z, 0, 0, 0);
      float16v d1 = __builtin_amdgcn_mfma_f32_32x32x16_bf16(af0, b1, z, 0, 0, 0);
      #pragma unroll
      for (int r = 0; r < 16; ++r)
        acc0[r] = fminf(fminf(d0[r], d1[r]), acc0[r]);  // v_min3_f32
      float16v d2 = __builtin_amdgcn_mfma_f32_32x32x16_bf16(af1, b0, z, 0, 0, 0);
      float16v d3 = __builtin_amdgcn_mfma_f32_32x32x16_bf16(af1, b1, z, 0, 0, 0);
      #pragma unroll
      for (int r = 0; r < 16; ++r)
        acc1[r] = fminf(fminf(d2[r], d3[r]), acc1[r]);
    }
  }

  // ---- Min across the 32 cols within each kg half (both acc sets) ----
  #pragma unroll
  for (int m = 1; m <= 16; m <<= 1) {
    #pragma unroll
    for (int r = 0; r < 16; ++r) {
      acc0[r] = fminf(acc0[r], __shfl_xor(acc0[r], m, 64));
      acc1[r] = fminf(acc1[r], __shfl_xor(acc1[r], m, 64));
    }
  }

  // ---- Epilogue: partial (this target-half) row-min d2 per query -> ws ----
  // qry LDS is dead (af-frags were consumed before the chunk-loop barriers);
  // reuse it as a [QPB] float staging buffer for coalesced ws stores.
  float* qmin = (float*)qry;
  if (n == 0) {  // lanes 0 and 32; each kg half holds disjoint row sets
    #pragma unroll
    for (int r = 0; r < 16; ++r) {
      const int row = (r & 3) + 8 * (r >> 2) + 4 * kg;
      qmin[wave * 64 + row] = acc0[r];
      qmin[wave * 64 + 32 + row] = acc1[r];
    }
  }
  __syncthreads();
  // Layout: ws[tc][dir][b][query] -- finish kernel pairs tc=0/1 at stride.
  ws[(size_t)tc * (2 * NBATCH * NPTS) + ((size_t)(dir * NBATCH + b)) * NPTS +
     qc * QPB + tid] = qmin[tid];
}

// min(half0, half1) -> sqrt -> sum -> atomicAdd. 256K floats read (1MB).
__global__ __launch_bounds__(THREADS)
void chamfer_finish(const float* __restrict__ ws, float* __restrict__ out) {
  __shared__ float red[THREADS / 64];
  const int tid = threadIdx.x;
  const int i4 = blockIdx.x * THREADS + tid;  // float4 index, 0..32767
  const float4 a = ((const float4*)ws)[i4];
  const float4 c = ((const float4*)ws)[(2 * NBATCH * NPTS / 4) + i4];
  float s = sqrtf(fmaxf(fminf(a.x, c.x), 0.0f)) +
            sqrtf(fmaxf(fminf(a.y, c.y), 0.0f)) +
            sqrtf(fmaxf(fminf(a.z, c.z), 0.0f)) +
            sqrtf(fmaxf(fminf(a.w, c.w), 0.0f));
  #pragma unroll
  for (int m = 1; m <= 32; m <<= 1) s += __shfl_xor(s, m, 64);
  if ((tid & 63) == 0) red[tid >> 6] = s;
  __syncthreads();
  if (tid == 0)
    atomicAdd(out, (red[0] + red[1] + red[2] + red[3]) * (0.01f / 16.0f));
}

extern "C" void kernel_launch(void* const* d_in, const int* in_sizes, int n_in,
                              void* d_out, int out_size, void* d_ws, size_t ws_size,
                              hipStream_t stream) {
  const float* shape = (const float*)d_in[0];
  const float* tmpl = (const float*)d_in[1];
  float* out = (float*)d_out;
  float* ws = (float*)d_ws;  // needs 2*2*16*4096*4 = 1 MB; no init required
                             // (every slot is plain-stored by exactly one block)

  // d_out is poisoned to 0xAA before every timed launch; atomics need zeros.
  hipMemsetAsync(out, 0, sizeof(float) * out_size, stream);

  // z encodes (target-half, dir): 16 x 16 x 4 = 1024 blocks -> 4 blocks/CU.
  dim3 grid(NPTS / QPB, NBATCH, 4);
  chamfer_mfma<<<grid, dim3(THREADS), 0, stream>>>(shape, tmpl, ws);
  chamfer_finish<<<dim3(2 * NBATCH * NPTS / 4 / THREADS), dim3(THREADS), 0, stream>>>(ws, out);
}

// Round 2
// 80.663 us; speedup vs baseline: 1.0272x; 1.0272x over previous
//
#include <hip/hip_runtime.h>

#define NPTS 4096
#define NBATCH 16
#define THREADS 256
#define QPB 128          // queries per block (4 waves x 32; 1 A-frag/wave)
#define TCH 1024         // targets per LDS chunk
#define NCH (NPTS / TCH) // 4 chunks

typedef __attribute__((ext_vector_type(8))) short short8;
typedef __attribute__((ext_vector_type(16))) float float16v;

static __device__ __forceinline__ unsigned short f2bf(float f) {
  unsigned int u = __builtin_bit_cast(unsigned int, f);
  u = (u + 0x7FFFu + ((u >> 16) & 1u)) >> 16;  // RNE
  return (unsigned short)u;
}
static __device__ __forceinline__ float bf2f(unsigned short h) {
  unsigned int u = ((unsigned int)h) << 16;
  return __builtin_bit_cast(float, u);
}
// Swizzled ushort offset of half-record h of target j (32B flat records,
// 16B-block XOR keyed by j's 128B group) -- staging writes & B-frag reads
// land on distinct banks (R8: verified correct, absmax 0.0).
static __device__ __forceinline__ int toff(int j, int h) {
  return (j * 16 + h * 8) ^ (((j >> 2) & 7) << 3);
}

// R12: REVERT to the R10 single-kernel structure (harness-verified 81.2us,
// absmax 0.0). Post-mortem of R11: halving LDS B-frag reads via 2 A-frags +
// ws spill/finish kernel REGRESSED 81.2 -> 82.9us. Counter evidence: the
// timed window is floored by ~2x40us unconditional 256MiB workspace-poison
// fills (268.4MB WRITE_SIZE each at 83-85% achievable HBM -- present even
// when the kernel never touches d_ws). The compute kernel (~7-13us) pipelines
// under the fills; intra-kernel gains are invisible. Touching d_ws creates a
// WAW dependency against the poison fill (partial serialization) plus a
// second launch = the +1.6us. Conclusion: single kernel, no workspace, is
// the floor configuration. Do not reintroduce d_ws usage.
//
// Kernel details (R10): d2 emitted directly by MFMA (K=13 of 16 slots):
//   A (query): [uhx,uhx,ulx, uhy,uhy,uly, uhz,uhz,ulz, 1,1, p2h,p2l, 0*3]
//   B (target):[thx,tlx,thx, thy,tly,thy, thz,tlz,thz, t2h,t2l, 1,1, 0*3]
// with u=-2p: sum_k A[k]B[k] = |p|^2 - 2p.t + |t|^2.
// 1 A-frag/wave (32 queries) keeps live regs ~90 < 128 -> clean 4 blocks/CU,
// 4 waves/SIMD without spills. Grid (32,16,2)=1024 blocks; block scans all
// 4096 targets in 4 LDS chunks; per tp: 2 ds_read_b128, 2 MFMA, 16 v_min3.
// Single kernel, atomicAdd epilogue, no workspace.
__global__ __launch_bounds__(THREADS)
__attribute__((amdgpu_waves_per_eu(4, 4)))
void chamfer_mfma(const float* __restrict__ shape,
                  const float* __restrict__ tmpl,
                  float* __restrict__ out) {
  __shared__ unsigned short tgt[TCH * 16];  // 32 KB swizzled records
  __shared__ unsigned short qry[QPB * 16];  // 4 KB flat records
  __shared__ float redbuf[4];

  const int qc = blockIdx.x;
  const int b = blockIdx.y;
  const int dir = blockIdx.z;
  const float* Pb = (dir == 0 ? shape : tmpl) + (size_t)b * NPTS * 3;
  const float* Tb = (dir == 0 ? tmpl : shape) + (size_t)b * NPTS * 3;

  const int tid = threadIdx.x;
  const int lane = tid & 63;
  const int wave = tid >> 6;
  const int n = lane & 31;   // MFMA row/col
  const int kg = lane >> 5;  // K-group: k = kg*8 + j

  // ---- Stage 128 queries: u=-2p split + p2 split record ----
  if (tid < QPB) {
    const int qg = qc * QPB + tid;
    const float px = Pb[3 * qg + 0], py = Pb[3 * qg + 1], pz = Pb[3 * qg + 2];
    const float ux = -2.0f * px, uy = -2.0f * py, uz = -2.0f * pz;
    const float p2 = fmaf(px, px, fmaf(py, py, pz * pz));
    const unsigned short hx = f2bf(ux), hy = f2bf(uy), hz = f2bf(uz);
    const unsigned short lx = f2bf(ux - bf2f(hx)), ly = f2bf(uy - bf2f(hy)),
                         lz = f2bf(uz - bf2f(hz));
    const unsigned short h2 = f2bf(p2), l2 = f2bf(p2 - bf2f(h2));
    const unsigned short ONE = 0x3F80;
    short8 v0, v1;
    v0[0] = hx; v0[1] = hx; v0[2] = lx; v0[3] = hy;
    v0[4] = hy; v0[5] = ly; v0[6] = hz; v0[7] = hz;
    v1[0] = lz; v1[1] = ONE; v1[2] = ONE; v1[3] = h2;
    v1[4] = l2; v1[5] = 0;  v1[6] = 0;  v1[7] = 0;
    *(short8*)&qry[tid * 16] = v0;
    *(short8*)&qry[tid * 16 + 8] = v1;
  }
  __syncthreads();

  // ---- One A-frag: wave w owns queries w*32 .. w*32+31 ----
  const short8 af = *(const short8*)&qry[(wave * 32 + n) * 16 + kg * 8];

  const float INF = 3.402823466e38f;
  float acc[16];
  #pragma unroll
  for (int r = 0; r < 16; ++r) acc[r] = INF;
  const float16v z = {};

  const float4* T4 = (const float4*)Tb;
  for (int ch = 0; ch < NCH; ++ch) {
    __syncthreads();
    // ---- Stage 1024 targets (4/thread: 3 float4 loads -> swizzled recs) ----
    {
      const int g = ch * (TCH / 4) + tid;
      const float4 a = T4[g * 3 + 0];
      const float4 c = T4[g * 3 + 1];
      const float4 d = T4[g * 3 + 2];
      const float X[4] = {a.x, a.w, c.z, d.y};
      const float Y[4] = {a.y, c.x, c.w, d.z};
      const float Z[4] = {a.z, c.y, d.x, d.w};
      #pragma unroll
      for (int p = 0; p < 4; ++p) {
        const float x = X[p], y = Y[p], zc = Z[p];
        const float t2 = fmaf(x, x, fmaf(y, y, zc * zc));
        const unsigned short hx = f2bf(x), hy = f2bf(y), hz = f2bf(zc);
        const unsigned short lx = f2bf(x - bf2f(hx)), ly = f2bf(y - bf2f(hy)),
                             lz = f2bf(zc - bf2f(hz));
        const unsigned short h2 = f2bf(t2), l2 = f2bf(t2 - bf2f(h2));
        const unsigned short ONE = 0x3F80;
        short8 v0, v1;
        v0[0] = hx; v0[1] = lx; v0[2] = hx; v0[3] = hy;
        v0[4] = ly; v0[5] = hy; v0[6] = hz; v0[7] = lz;
        v1[0] = hz; v1[1] = h2; v1[2] = l2; v1[3] = ONE;
        v1[4] = ONE; v1[5] = 0; v1[6] = 0; v1[7] = 0;
        const int j = tid * 4 + p;
        *(short8*)&tgt[toff(j, 0)] = v0;
        *(short8*)&tgt[toff(j, 1)] = v1;
      }
    }
    __syncthreads();

    // ---- 16 tile-pairs: 2 reads -> 2 MFMA -> 16 min3 ----
    for (int tp = 0; tp < TCH / 64; ++tp) {
      const short8 b0 = *(const short8*)&tgt[toff(tp * 64 + n, kg)];
      const short8 b1 = *(const short8*)&tgt[toff(tp * 64 + 32 + n, kg)];
      float16v d0 = __builtin_amdgcn_mfma_f32_32x32x16_bf16(af, b0, z, 0, 0, 0);
      float16v d1 = __builtin_amdgcn_mfma_f32_32x32x16_bf16(af, b1, z, 0, 0, 0);
      #pragma unroll
      for (int r = 0; r < 16; ++r)
        acc[r] = fminf(fminf(d0[r], d1[r]), acc[r]);  // v_min3_f32
    }
  }

  // ---- Min across the 32 cols within each kg half ----
  #pragma unroll
  for (int m = 1; m <= 16; m <<= 1) {
    #pragma unroll
    for (int r = 0; r < 16; ++r)
      acc[r] = fminf(acc[r], __shfl_xor(acc[r], m, 64));
  }

  // ---- Epilogue: lanes 0/32 hold disjoint row sets; sqrt+reduce+atomic ----
  float s = 0.0f;
  if (n == 0) {
    #pragma unroll
    for (int r = 0; r < 16; ++r)
      s += sqrtf(fmaxf(acc[r], 0.0f));
  }
  s += __shfl_xor(s, 32, 64);  // combine kg=0 / kg=1 partial sums
  if (lane == 0) redbuf[wave] = s;
  __syncthreads();
  if (tid == 0) {
    // out = 0.01 * mean over 16 batches of per-batch chamfer sums
    atomicAdd(out, (redbuf[0] + redbuf[1] + redbuf[2] + redbuf[3]) * (0.01f / 16.0f));
  }
}

extern "C" void kernel_launch(void* const* d_in, const int* in_sizes, int n_in,
                              void* d_out, int out_size, void* d_ws, size_t ws_size,
                              hipStream_t stream) {
  const float* shape = (const float*)d_in[0];
  const float* tmpl = (const float*)d_in[1];
  float* out = (float*)d_out;

  // d_out is poisoned to 0xAA before every timed launch; atomics need zeros.
  hipMemsetAsync(out, 0, sizeof(float) * out_size, stream);

  dim3 grid(NPTS / QPB, NBATCH, 2);
  chamfer_mfma<<<grid, dim3(THREADS), 0, stream>>>(shape, tmpl, out);
}